// Round 14
// baseline (389.661 us; speedup 1.0000x reference)
//
#include <hip/hip_runtime.h>
#include <hip/hip_bf16.h>

#define Bdim 64
#define Tdim 96
#define Pdim 256
#define Hdim 128
#define Gdim 512   // 4*H
#define Odim 24
#define BH   32    // batches per stream (two streams per block)

typedef _Float16 f16x8 __attribute__((ext_vector_type(8)));
typedef float    f32x16 __attribute__((ext_vector_type(16)));
typedef float    f32x2  __attribute__((ext_vector_type(2)));

union H8 { uint4 u4; unsigned short s[8]; _Float16 h[8]; f16x8 v; };
union HS { _Float16 h; unsigned short s; };

__device__ __forceinline__ float exp2_fast(float x) {
#if __has_builtin(__builtin_amdgcn_exp2f)
    return __builtin_amdgcn_exp2f(x);
#else
    return __expf(x * 0.6931471805599453f);
#endif
}

// R9 (4th resubmit; repeated GPU-acquisition timeouts): instruction-count
// reduction. R2/R5/R6 = three different schedules, all EXACTLY 330us /
// VALUBusy 55 / Mfma 32 / Occ 44 -> issue-volume-bound (55+32 ~= 87% combined,
// near saturation per m98's 80% reference), schedule changes are dead. Remove
// VALU instructions instead:
//  1. t-loop manually unrolled x2 -> buffer parity compile-time -> ds base
//     folds into the 16-bit offset: immediate; no runtime rb/wb selects.
//  2. per-lane LDS offsets (dsoff[8], write base) hoisted out of the loop as
//     loop-invariant VGPRs (statically indexed only).
//  3. gx B-operand packed via direct u4 writes (no 8-short zero loop).
// Math, layout, schedule otherwise identical to R6 (verified absmax 9.77e-4).
// Gates: FETCH ~60 MB (no spill), VGPR<=128.
//
// h storage: row b = 256 B = 16 chunks of 16 B, chunk c at position c ^ (b&15)
// (XOR swizzle). Gemm read of chunk c = 2ks+hi by lane b=l31 is ONE aligned
// ds_read_b128 at byte offset 256*l31 + 16*(c^(l31&15)) -> balanced banks.
// Rotated k-map (R5): kl = rot(u) makes each lane's 4 h outputs contiguous ->
// epilogue writes are ONE ds_write_b64 per wave per stream (conflict-fixed).
//
// Math: log2e-prescaled weights (2log2e for g), gx fused as 9th MFMA K-step,
// scaled-domain cell state, paired-rcp epilogue (6 trans per (b,k)).
__global__ __launch_bounds__(1024, 4)
void lstm_fused(const float* __restrict__ x,
                const float* __restrict__ W_ih,
                const float* __restrict__ W_hh,
                const float* __restrict__ b_ih,
                const float* __restrict__ b_hh,
                const float* __restrict__ W_fc,
                const float* __restrict__ b_fc,
                float* __restrict__ out)
{
    __shared__ alignas(16) unsigned short hb0[2][BH * Hdim];  // stream0 h, dbuf, swizzled
    __shared__ alignas(16) unsigned short hb1[2][BH * Hdim];  // stream1 h, dbuf, swizzled

    const int p   = blockIdx.x;
    const int tid = threadIdx.x;
    const int w   = tid >> 6;    // wave 0..15
    const int l31 = tid & 31;
    const int hi  = (tid >> 5) & 1;

    const float L1 = 1.4426950408889634f;  // log2(e)
    const float L2 = 2.0f * L1;

    for (int i = tid; i < 2 * BH * Hdim; i += 1024) ((unsigned short*)hb0)[i] = 0;
    for (int i = tid; i < 2 * BH * Hdim; i += 1024) ((unsigned short*)hb1)[i] = 0;

    // ---- loop-invariant LDS addresses (bytes) ----
    int dsoff[8];
    #pragma unroll
    for (int ks = 0; ks < 8; ++ks)
        dsoff[ks] = (l31 << 8) + ((((ks * 2 + hi)) ^ (l31 & 15)) << 4);
    const int wbyte = (l31 << 8) + ((w ^ (l31 & 15)) << 4) + (hi << 3);

    // ---- preload shared A fragments (time-invariant): W_hh rows + gx row ----
    // Rotated row map (R5): gate = r&3, k_local = rot(u)=((u&1)<<2)|(u>>1) so a
    // lane's 4 epilogue outputs are contiguous shorts; chunk invariant kept.
    f16x8 afr[9];
    {
        const int rp   = w * 32 + l31;                 // block row id
        const int u    = l31 >> 2;                     // 3-bit within-chunk idx
        const int kl   = ((u & 1) << 2) | (u >> 1);    // rotated
        const int orow = ((rp & 3) << 7) | (w * 8 + kl); // gate*128 + k
        const float sc = ((rp & 3) == 2) ? L2 : L1;    // g gate: 2*log2e
        const float* rowp = W_hh + (size_t)p * Gdim * Hdim + (size_t)orow * Hdim;
        #pragma unroll
        for (int ks = 0; ks < 8; ++ks) {
            int k0 = ks * 16 + hi * 8;
            float4 va = *(const float4*)(rowp + k0);
            float4 vb = *(const float4*)(rowp + k0 + 4);
            H8 u8;
            u8.h[0] = (_Float16)(sc * va.x); u8.h[1] = (_Float16)(sc * va.y);
            u8.h[2] = (_Float16)(sc * va.z); u8.h[3] = (_Float16)(sc * va.w);
            u8.h[4] = (_Float16)(sc * vb.x); u8.h[5] = (_Float16)(sc * vb.y);
            u8.h[6] = (_Float16)(sc * vb.z); u8.h[7] = (_Float16)(sc * vb.w);
            afr[ks] = u8.v;
        }
        H8 u9;
        #pragma unroll
        for (int j = 0; j < 8; ++j) u9.s[j] = 0;
        if (hi == 0) {
            u9.h[0] = (_Float16)(sc * W_ih[(size_t)p * Gdim + orow]);
            u9.h[1] = (_Float16)(sc * (b_ih[(size_t)p * Gdim + orow] +
                                       b_hh[(size_t)p * Gdim + orow]));
        }
        afr[8] = u9.v;
    }

    // epilogue for q-pair j: acc -> new c (in cr), returns packed 2xf16 h
    auto ep_pair = [&](const f32x16& a, int j, f32x2* cr) -> unsigned {
        f32x2 yi = {a[8 * j + 0], a[8 * j + 4]};
        f32x2 yf = {a[8 * j + 1], a[8 * j + 5]};
        f32x2 yg = {a[8 * j + 2], a[8 * j + 6]};   // prescaled by 2*log2e
        f32x2 yo = {a[8 * j + 3], a[8 * j + 7]};
        f32x2 Ef = {exp2_fast(-yf.x), exp2_fast(-yf.y)};
        f32x2 Ei = {exp2_fast(-yi.x), exp2_fast(-yi.y)};
        f32x2 Eg = {exp2_fast(yg.x),  exp2_fast(yg.y)};
        f32x2 t1 = Ef + 1.0f;
        f32x2 t2 = Ei + 1.0f;
        f32x2 t3 = Eg + 1.0f;
        f32x2 t4 = Eg - 1.0f;
        f32x2 den = (t1 * t2) * t3;
        f32x2 num = (cr[j] * t2) * t3 + (L2 * t4) * t1;
        float D = den.x * den.y;
        float r = __builtin_amdgcn_rcpf(D);
        f32x2 inv = {r * den.y, r * den.x};
        f32x2 cn  = num * inv;
        cn.x = __builtin_amdgcn_fmed3f(cn.x, -30.0f, 30.0f);
        cn.y = __builtin_amdgcn_fmed3f(cn.y, -30.0f, 30.0f);
        cr[j] = cn;
        f32x2 Eo = {exp2_fast(-yo.x), exp2_fast(-yo.y)};
        f32x2 Ec = {exp2_fast(cn.x),  exp2_fast(cn.y)};
        f32x2 d2 = (Eo + 1.0f) * (Ec + 1.0f);
        float D2 = d2.x * d2.y;
        float r2 = __builtin_amdgcn_rcpf(D2);
        f32x2 j2 = {r2 * d2.y, r2 * d2.x};
        f32x2 hv = (Ec - 1.0f) * j2;
        HS ha; ha.h = (_Float16)hv.x;
        HS hc; hc.h = (_Float16)hv.y;
        return (unsigned)ha.s | ((unsigned)hc.s << 16);
    };

    f32x2 cre0[2] = {f32x2{0.f, 0.f}, f32x2{0.f, 0.f}};
    f32x2 cre1[2] = {f32x2{0.f, 0.f}, f32x2{0.f, 0.f}};

    // one step: fused gemm (two interleaved 9-MFMA chains) + both epilogues.
    // rb*/wbuf* are literal __shared__ arrays at every call site -> ds offsets
    // fold to immediates.
    auto step = [&](const unsigned short* rb0, const unsigned short* rb1,
                    unsigned short* wbuf0, unsigned short* wbuf1,
                    float xa, float xb) {
        const char* r0 = (const char*)rb0;
        const char* r1 = (const char*)rb1;
        f32x16 acc0, acc1;
        {
            f32x16 z;
            #pragma unroll
            for (int j = 0; j < 16; ++j) z[j] = 0.f;
            unsigned pk0 = 0, pk1 = 0;
            if (hi == 0) {
                HS bx0; bx0.h = (_Float16)xa;
                HS bx1; bx1.h = (_Float16)xb;
                pk0 = (unsigned)bx0.s | (0x3C00u << 16);
                pk1 = (unsigned)bx1.s | (0x3C00u << 16);
            }
            H8 bg0; bg0.u4.x = pk0; bg0.u4.y = 0; bg0.u4.z = 0; bg0.u4.w = 0;
            H8 bg1; bg1.u4.x = pk1; bg1.u4.y = 0; bg1.u4.z = 0; bg1.u4.w = 0;
            acc0 = __builtin_amdgcn_mfma_f32_32x32x16_f16(afr[8], bg0.v, z, 0, 0, 0);
            acc1 = __builtin_amdgcn_mfma_f32_32x32x16_f16(afr[8], bg1.v, z, 0, 0, 0);
            H8 a0, b0, a1, b1, a2, b2, a3, b3, a4, b4, a5, b5, a6, b6, a7, b7;
            a0.u4 = *(const uint4*)(r0 + dsoff[0]);
            b0.u4 = *(const uint4*)(r1 + dsoff[0]);
            a1.u4 = *(const uint4*)(r0 + dsoff[1]);
            b1.u4 = *(const uint4*)(r1 + dsoff[1]);
            acc0 = __builtin_amdgcn_mfma_f32_32x32x16_f16(afr[0], a0.v, acc0, 0, 0, 0);
            acc1 = __builtin_amdgcn_mfma_f32_32x32x16_f16(afr[0], b0.v, acc1, 0, 0, 0);
            a2.u4 = *(const uint4*)(r0 + dsoff[2]);
            b2.u4 = *(const uint4*)(r1 + dsoff[2]);
            acc0 = __builtin_amdgcn_mfma_f32_32x32x16_f16(afr[1], a1.v, acc0, 0, 0, 0);
            acc1 = __builtin_amdgcn_mfma_f32_32x32x16_f16(afr[1], b1.v, acc1, 0, 0, 0);
            a3.u4 = *(const uint4*)(r0 + dsoff[3]);
            b3.u4 = *(const uint4*)(r1 + dsoff[3]);
            acc0 = __builtin_amdgcn_mfma_f32_32x32x16_f16(afr[2], a2.v, acc0, 0, 0, 0);
            acc1 = __builtin_amdgcn_mfma_f32_32x32x16_f16(afr[2], b2.v, acc1, 0, 0, 0);
            a4.u4 = *(const uint4*)(r0 + dsoff[4]);
            b4.u4 = *(const uint4*)(r1 + dsoff[4]);
            acc0 = __builtin_amdgcn_mfma_f32_32x32x16_f16(afr[3], a3.v, acc0, 0, 0, 0);
            acc1 = __builtin_amdgcn_mfma_f32_32x32x16_f16(afr[3], b3.v, acc1, 0, 0, 0);
            a5.u4 = *(const uint4*)(r0 + dsoff[5]);
            b5.u4 = *(const uint4*)(r1 + dsoff[5]);
            acc0 = __builtin_amdgcn_mfma_f32_32x32x16_f16(afr[4], a4.v, acc0, 0, 0, 0);
            acc1 = __builtin_amdgcn_mfma_f32_32x32x16_f16(afr[4], b4.v, acc1, 0, 0, 0);
            a6.u4 = *(const uint4*)(r0 + dsoff[6]);
            b6.u4 = *(const uint4*)(r1 + dsoff[6]);
            acc0 = __builtin_amdgcn_mfma_f32_32x32x16_f16(afr[5], a5.v, acc0, 0, 0, 0);
            acc1 = __builtin_amdgcn_mfma_f32_32x32x16_f16(afr[5], b5.v, acc1, 0, 0, 0);
            a7.u4 = *(const uint4*)(r0 + dsoff[7]);
            b7.u4 = *(const uint4*)(r1 + dsoff[7]);
            acc0 = __builtin_amdgcn_mfma_f32_32x32x16_f16(afr[6], a6.v, acc0, 0, 0, 0);
            acc1 = __builtin_amdgcn_mfma_f32_32x32x16_f16(afr[6], b6.v, acc1, 0, 0, 0);
            acc0 = __builtin_amdgcn_mfma_f32_32x32x16_f16(afr[7], a7.v, acc0, 0, 0, 0);
            acc1 = __builtin_amdgcn_mfma_f32_32x32x16_f16(afr[7], b7.v, acc1, 0, 0, 0);
        }
        {
            unsigned e00 = ep_pair(acc0, 0, cre0);
            unsigned e01 = ep_pair(acc0, 1, cre0);
            uint2 v0; v0.x = e00; v0.y = e01;
            *(uint2*)((char*)wbuf0 + wbyte) = v0;
            unsigned e10 = ep_pair(acc1, 0, cre1);
            unsigned e11 = ep_pair(acc1, 1, cre1);
            uint2 v1; v1.x = e10; v1.y = e11;
            *(uint2*)((char*)wbuf1 + wbyte) = v1;
        }
    };

    const float* xp0 = x + (size_t)((0 * BH + l31) * Tdim) * Pdim + p;
    const float* xp1 = x + (size_t)((1 * BH + l31) * Tdim) * Pdim + p;
    float xv0 = xp0[0];
    float xv1 = xp1[0];

    __syncthreads();

    // unrolled x2: even t reads buffer 0 / writes 1; odd t reads 1 / writes 0.
    for (int t = 0; t < Tdim; t += 2) {
        // prefetch x(t+1) (t+1 <= 95 always here)
        float xn0 = xp0[(size_t)(t + 1) * Pdim];
        float xn1 = xp1[(size_t)(t + 1) * Pdim];
        step(hb0[0], hb1[0], hb0[1], hb1[1], xv0, xv1);
        __syncthreads();
        xv0 = xn0; xv1 = xn1;
        // prefetch x(t+2), clamped at the tail (value unused after last step)
        const int tn = (t + 2 < Tdim) ? (t + 2) : (Tdim - 1);
        xn0 = xp0[(size_t)tn * Pdim];
        xn1 = xp1[(size_t)tn * Pdim];
        step(hb0[1], hb1[1], hb0[0], hb1[0], xv0, xv1);
        __syncthreads();
        xv0 = xn0; xv1 = xn1;
    }
    // final h (t=95 writes buffer 0): stream0 in hb0[0], stream1 in hb1[0]

    // ---- FC: out[b][o][p] = sum_k W_fc[p][o][k]*h[b][k] + b_fc[p][o] ----
    const float* wfc = W_fc + (size_t)p * Odim * Hdim;
    const float* bfc = b_fc + (size_t)p * Odim;
    for (int i = tid; i < Bdim * Odim; i += 1024) {
        int o = i % Odim;
        int b = i / Odim;            // global batch 0..63
        int bl = (b < BH) ? b : (b - BH);
        const unsigned short* hr = (b < BH) ? (hb0[0] + (bl << 7))
                                            : (hb1[0] + (bl << 7));
        float s = bfc[o];
        const float* wr = wfc + o * Hdim;
        #pragma unroll 8
        for (int k2 = 0; k2 < Hdim; ++k2) {
            int idx = (((k2 >> 3) ^ (bl & 15)) << 3) + (k2 & 7);   // unswizzle
            HS s2; s2.s = hr[idx];
            s = __builtin_fmaf(wr[k2], (float)s2.h, s);
        }
        out[(size_t)b * Odim * Pdim + (size_t)o * Pdim + p] = s;
    }
}

extern "C" void kernel_launch(void* const* d_in, const int* in_sizes, int n_in,
                              void* d_out, int out_size, void* d_ws, size_t ws_size,
                              hipStream_t stream) {
    const float* x    = (const float*)d_in[0];
    const float* W_ih = (const float*)d_in[1];
    const float* W_hh = (const float*)d_in[2];
    const float* b_ih = (const float*)d_in[3];
    const float* b_hh = (const float*)d_in[4];
    const float* W_fc = (const float*)d_in[5];
    const float* b_fc = (const float*)d_in[6];
    float* out = (float*)d_out;

    lstm_fused<<<dim3(Pdim), dim3(1024), 0, stream>>>(x, W_ih, W_hh, b_ih, b_hh, W_fc, b_fc, out);
}